// Round 4
// baseline (1609.830 us; speedup 1.0000x reference)
//
#include <hip/hip_runtime.h>

// Fastformer additive attention, MI355X (round 3): runtime dtype detection.
// Rounds 1-2 NaN'd independent of workspace footprint => inputs are very
// likely f32 (per the reference), not bf16. A detector kernel sniffs x's bit
// patterns and sets a mode flag in d_ws; all compute kernels are templated on
// the element type and launched in both variants with a flag guard.
//
// Math (vs reference):
//   q/k/v[b,h,n,d] = x[b,n,:] @ w_qkv[{0,512,1024}+h*64+d, :]^T + b_qkv[...]
//   qs[b,h,n] = sum_d q = x·colsum(Wq_h) + sum_d bq_h   (wsum table)
//   L1[n,m] = (q[n]·wq[m]+bq[m])*S ; qg = sum_m softmax(L1)*qs[m]
//   L2[n,m] = (qg[n]*(k[n]·wk[m])+bk[m])*S ; kg = sum_m softmax(L2)*(qg*ks)[m]
//   out[n,j] = sum_i (kg*v)[n,i]·w_out[j,i] + sum_p x[n,p]·w_qkv[j,p]
//              + b_out[j] + b_qkv[j]          (qo residual folded, K=1024)
// Logits bounded (|l|<~2): softmax without max subtraction is exact here.
// Workspace: flag + qs|ks|qg|kg + wsumT|bsum  ~= 1.1 MB.

#define NSEQ  1024
#define DIMM  512
#define SCL   0.125f

typedef unsigned short u16;

__device__ __forceinline__ float bf2f(u16 u) {
    union { unsigned int i; float f; } v; v.i = ((unsigned int)u) << 16; return v.f;
}
__device__ __forceinline__ u16 f2bf(float f) {
    union { float f; unsigned int i; } v; v.f = f;
    unsigned int x = v.i;
    return (u16)((x + 0x7FFFu + ((x >> 16) & 1u)) >> 16);
}

// MODE: 0 = f32 storage, 1 = bf16 storage
template <typename T> __device__ __forceinline__ constexpr int mode_of() {
    return sizeof(T) == 2 ? 1 : 0;
}
template <typename T>
__device__ __forceinline__ void load4(const T* p, float* o) {
    if constexpr (sizeof(T) == 2) {
        ushort4 u = *(const ushort4*)p;
        o[0] = bf2f(u.x); o[1] = bf2f(u.y); o[2] = bf2f(u.z); o[3] = bf2f(u.w);
    } else {
        float4 u = *(const float4*)p;
        o[0] = u.x; o[1] = u.y; o[2] = u.z; o[3] = u.w;
    }
}
template <typename T>
__device__ __forceinline__ float load1(const T* p) {
    if constexpr (sizeof(T) == 2) return bf2f(*p);
    else return *p;
}

// ---------------------------------------------------------------------------
// Dtype detector. Samples 4096 u16s of x.
//  - genuine bf16 N(0,1): exponent field <= ~0x82, never 0; counts stay 0.
//  - raw f32: even-index u16s are random mantissa bits -> ~44% have exp>=0x90.
//  - bf16-rounded f32: even-index u16s are exactly 0 -> zero count ~2048.
// ---------------------------------------------------------------------------
__global__ __launch_bounds__(256) void detect_kernel(const u16* __restrict__ x,
                                                     int* __restrict__ flag)
{
    __shared__ int sbe, sze;
    if (threadIdx.x == 0) { sbe = 0; sze = 0; }
    __syncthreads();
    int be = 0, ze = 0;
    for (int i = threadIdx.x; i < 4096; i += 256) {
        const u16 v = x[i];
        const int e = (v >> 7) & 0xFF;
        be += (e >= 0x90);
        ze += (v == 0);
    }
    atomicAdd(&sbe, be); atomicAdd(&sze, ze);
    __syncthreads();
    if (threadIdx.x == 0) flag[0] = (sbe > 8 || sze > 64) ? 0 : 1;
}

// ---------------------------------------------------------------------------
// wsumT[k][c] (c = qk*8+h) = sum_d w_qkv[qk*512 + h*64 + d][k]
// bsum[c]    = sum_d b_qkv[qk*512 + h*64 + d]
// ---------------------------------------------------------------------------
template <typename T>
__global__ __launch_bounds__(256) void wsum_kernel(
    const int* __restrict__ flag,
    const T* __restrict__ w_qkv, const T* __restrict__ b_qkv,
    float* __restrict__ wsumT, float* __restrict__ bsum)
{
    if (flag[0] != mode_of<T>()) return;
    const int c = blockIdx.x;           // 0..15
    const int rowbase = (c >> 3) * 512 + (c & 7) * 64;
    for (int k = threadIdx.x; k < 512; k += 256) {
        float s = 0.f;
        for (int d = 0; d < 64; ++d)
            s += load1(w_qkv + (size_t)(rowbase + d) * 512 + k);
        wsumT[k * 16 + c] = s;
    }
    if (threadIdx.x == 0) {
        float s = 0.f;
        for (int d = 0; d < 64; ++d) s += load1(b_qkv + rowbase + d);
        bsum[c] = s;
    }
}

// ---------------------------------------------------------------------------
// qs[b,h,n] / ks[b,h,n] = x[row]·wsumT[:,c] + bsum[c].  Block: 16 rows x 16 c.
// ---------------------------------------------------------------------------
template <typename T>
__global__ __launch_bounds__(256) void qsks_kernel(
    const int* __restrict__ flag,
    const T* __restrict__ x, const float* __restrict__ wsumT,
    const float* __restrict__ bsum,
    float* __restrict__ qs, float* __restrict__ ks)
{
    if (flag[0] != mode_of<T>()) return;
    __shared__ float X[16][512];
    const int t = threadIdx.x;
    const int rowbase = blockIdx.x * 16;
    {
        const int nr = t >> 4, seg = t & 15;
        const T* xp = x + (size_t)(rowbase + nr) * 512 + seg * 32;
#pragma unroll
        for (int q = 0; q < 8; ++q)
            load4(xp + q * 4, &X[nr][seg * 32 + q * 4]);
    }
    __syncthreads();
    const int nr = t >> 4, c = t & 15;
    float dot = bsum[c];
    for (int k = 0; k < 512; ++k)
        dot += X[nr][k] * wsumT[k * 16 + c];
    const int r = rowbase + nr;
    const int idx = ((((r >> 10) << 3) + (c & 7)) << 10) + (r & 1023);
    if (c < 8) qs[idx] = dot; else ks[idx] = dot;
}

// ---------------------------------------------------------------------------
// Fused additive-attention stage with in-kernel q/k recompute.
// Block: (n-tile of 64) x (b,h).  Phase 1: Q[d][n] = x-tile @ W_h^T + bias
// (K=512, BK=64).  Phase 2: loop 16 m-tiles of wq/wk, logits GEMM (K=64),
// exp + weighted accumulation; one LDS reduction at the end.
//   stage1: aoff=0,   rowscale=null, wv = qs
//   stage2: aoff=512, rowscale=qg,   wv = qg*ks
// ---------------------------------------------------------------------------
template <typename T>
__global__ __launch_bounds__(256) void stage_kernel(
    const int* __restrict__ flag,
    const T* __restrict__ x, const T* __restrict__ w_qkv,
    const T* __restrict__ b_qkv, int aoff,
    const T* __restrict__ wmat,      // [1024][64]
    const T* __restrict__ biasv,     // [1024]
    const float* __restrict__ rowscale,
    const float* __restrict__ wv1,
    const float* __restrict__ wv2,
    float* __restrict__ outg)
{
    if (flag[0] != mode_of<T>()) return;
    __shared__ float SA[64][64];   // phase1: x-tile [k][n];  phase2: w-tile [d][m]
    __shared__ float SB[64][64];   // phase1: W_h [k][d];     end: zr/wr
    __shared__ float Q[64][64];    // q-tile [d][n], persistent

    const int t  = threadIdx.x;
    const int tx = t & 15, ty = t >> 4;
    const int n0 = blockIdx.x * 64;
    const int bh = blockIdx.y;
    const int b = bh >> 3, h = bh & 7;
    const int lrow = t & 63;
    const int kb = (t >> 6) * 16;

    // ---- phase 1: Q[d][n] ----
    float acc[4][4] = {};
    for (int kt = 0; kt < 512; kt += 64) {
        {
            const T* xp = x + (size_t)((b << 10) + n0 + lrow) * DIMM + kt + kb;
            const T* wp = w_qkv + (size_t)(aoff + (h << 6) + lrow) * DIMM + kt + kb;
#pragma unroll
            for (int q = 0; q < 4; ++q) {
                float v[4]; load4(xp + q * 4, v);
                SA[kb + q * 4 + 0][lrow] = v[0]; SA[kb + q * 4 + 1][lrow] = v[1];
                SA[kb + q * 4 + 2][lrow] = v[2]; SA[kb + q * 4 + 3][lrow] = v[3];
                float w[4]; load4(wp + q * 4, w);
                SB[kb + q * 4 + 0][lrow] = w[0]; SB[kb + q * 4 + 1][lrow] = w[1];
                SB[kb + q * 4 + 2][lrow] = w[2]; SB[kb + q * 4 + 3][lrow] = w[3];
            }
        }
        __syncthreads();
#pragma unroll
        for (int k = 0; k < 64; ++k) {
            float4 a4 = *(const float4*)&SA[k][ty * 4];
            float4 b4 = *(const float4*)&SB[k][tx * 4];
            float av[4] = {a4.x, a4.y, a4.z, a4.w};
            float bv[4] = {b4.x, b4.y, b4.z, b4.w};
#pragma unroll
            for (int i = 0; i < 4; ++i)
#pragma unroll
                for (int j = 0; j < 4; ++j)
                    acc[i][j] = fmaf(av[i], bv[j], acc[i][j]);
        }
        __syncthreads();
    }
    {   // Q[d][n] = acc + head bias (d = tx*4+j, n = ty*4+i)
        float bb[4]; load4(b_qkv + aoff + (h << 6) + tx * 4, bb);
#pragma unroll
        for (int i = 0; i < 4; ++i)
#pragma unroll
            for (int j = 0; j < 4; ++j)
                Q[tx * 4 + j][ty * 4 + i] = acc[i][j] + bb[j];
    }

    float rs[4];
#pragma unroll
    for (int i = 0; i < 4; ++i)
        rs[i] = rowscale ? rowscale[(bh << 10) + n0 + ty * 4 + i] : 1.0f;

    // ---- phase 2: softmax-weighted accumulation over m ----
    float z[4] = {0, 0, 0, 0}, w[4] = {0, 0, 0, 0};
    for (int mt = 0; mt < NSEQ; mt += 64) {
        {
            const T* wp = wmat + (size_t)(mt + lrow) * 64 + kb;
#pragma unroll
            for (int q = 0; q < 4; ++q) {
                float u[4]; load4(wp + q * 4, u);
                SA[kb + q * 4 + 0][lrow] = u[0]; SA[kb + q * 4 + 1][lrow] = u[1];
                SA[kb + q * 4 + 2][lrow] = u[2]; SA[kb + q * 4 + 3][lrow] = u[3];
            }
        }
        __syncthreads();
        float acc2[4][4] = {};
#pragma unroll
        for (int d = 0; d < 64; ++d) {
            float4 a4 = *(const float4*)&Q[d][ty * 4];
            float4 b4 = *(const float4*)&SA[d][tx * 4];
            float av[4] = {a4.x, a4.y, a4.z, a4.w};
            float bv[4] = {b4.x, b4.y, b4.z, b4.w};
#pragma unroll
            for (int i = 0; i < 4; ++i)
#pragma unroll
                for (int j = 0; j < 4; ++j)
                    acc2[i][j] = fmaf(av[i], bv[j], acc2[i][j]);
        }
        const int mb = mt + tx * 4;
        float bb[4]; load4(biasv + mb, bb);
        float wv[4];
#pragma unroll
        for (int j = 0; j < 4; ++j) {
            float v = wv1[(bh << 10) + mb + j];
            if (wv2) v *= wv2[(bh << 10) + mb + j];
            wv[j] = v;
        }
#pragma unroll
        for (int i = 0; i < 4; ++i)
#pragma unroll
            for (int j = 0; j < 4; ++j) {
                const float l = (rs[i] * acc2[i][j] + bb[j]) * SCL;
                const float e = __expf(l);
                z[i] += e;
                w[i] += e * wv[j];
            }
        __syncthreads();
    }

    // ---- final per-row reduction across the 16 column-threads ----
    float (*zr)[17] = (float(*)[17]) & SB[0][0];
    float (*wr)[17] = zr + 64;
#pragma unroll
    for (int i = 0; i < 4; ++i) {
        zr[ty * 4 + i][tx] = z[i];
        wr[ty * 4 + i][tx] = w[i];
    }
    __syncthreads();
    if (t < 64) {
        float Z = 0.f, W = 0.f;
#pragma unroll
        for (int i = 0; i < 16; ++i) { Z += zr[t][i]; W += wr[t][i]; }
        outg[(bh << 10) + n0 + t] = W / Z;
    }
}

// ---------------------------------------------------------------------------
// Output kernel. Block: 32 m-rows, all 512 j.
// Phase 1: U[i][n] = bf16( kg[b,i/64,n] * (x@Wv^T + bv)[n,i] ), i-tiles of 64.
// Phase 2: out[n,j] = sum_{k<512} x[n,k] w_qkv[j,k] + sum_i U[i][n] w_out[j,i]
//                     + b_out[j] + b_qkv[j]    (K=1024 concat GEMM)
// ---------------------------------------------------------------------------
template <typename T>
__global__ __launch_bounds__(256) void out_kernel(
    const int* __restrict__ flag,
    const T* __restrict__ x, const T* __restrict__ w_qkv,
    const T* __restrict__ b_qkv, const T* __restrict__ w_out,
    const T* __restrict__ b_out, const float* __restrict__ kg,
    void* __restrict__ outv)
{
    if (flag[0] != mode_of<T>()) return;
    __shared__ u16   U[512][32];   // 32 KB, persistent (bf16 repack)
    __shared__ float XA[64][32];   // x-tile [k][n]
    __shared__ float WB[64][64];   // weight tile [k][j or d]

    const int t  = threadIdx.x;
    const int tx = t & 15, ty = t >> 4;      // cols j=tx*4.., rows n=ty*2..
    const int mbase = blockIdx.x * 32;
    const int b = mbase >> 10, nloc = mbase & 1023;
    const int xan = t & 31, xak = (t >> 5) * 8;
    const int wbd = t & 63, wbk = (t >> 6) * 16;

    // ---- phase 1: build U ----
    for (int it = 0; it < 8; ++it) {
        float acc[2][4] = {};
        for (int kt = 0; kt < 512; kt += 64) {
            {
                const T* xp = x + (size_t)(mbase + xan) * DIMM + kt + xak;
#pragma unroll
                for (int q = 0; q < 2; ++q)
                    load4(xp + q * 4, &XA[xak + q * 4][0] + xan - (size_t)0),
                    ((void)0);
                // (rewritten without pointer trick below)
                float v0[4], v1[4];
                load4(xp, v0); load4(xp + 4, v1);
                XA[xak + 0][xan] = v0[0]; XA[xak + 1][xan] = v0[1];
                XA[xak + 2][xan] = v0[2]; XA[xak + 3][xan] = v0[3];
                XA[xak + 4][xan] = v1[0]; XA[xak + 5][xan] = v1[1];
                XA[xak + 6][xan] = v1[2]; XA[xak + 7][xan] = v1[3];
                const T* wp = w_qkv + (size_t)(1024 + (it << 6) + wbd) * DIMM + kt + wbk;
#pragma unroll
                for (int q = 0; q < 4; ++q) {
                    float w[4]; load4(wp + q * 4, w);
                    WB[wbk + q * 4 + 0][wbd] = w[0]; WB[wbk + q * 4 + 1][wbd] = w[1];
                    WB[wbk + q * 4 + 2][wbd] = w[2]; WB[wbk + q * 4 + 3][wbd] = w[3];
                }
            }
            __syncthreads();
#pragma unroll
            for (int k = 0; k < 64; ++k) {
                const float a0 = XA[k][ty * 2], a1 = XA[k][ty * 2 + 1];
                float4 b4 = *(const float4*)&WB[k][tx * 4];
                float bv[4] = {b4.x, b4.y, b4.z, b4.w};
#pragma unroll
                for (int j = 0; j < 4; ++j) {
                    acc[0][j] = fmaf(a0, bv[j], acc[0][j]);
                    acc[1][j] = fmaf(a1, bv[j], acc[1][j]);
                }
            }
            __syncthreads();
        }
        float bb[4]; load4(b_qkv + 1024 + (it << 6) + tx * 4, bb);
#pragma unroll
        for (int i = 0; i < 2; ++i) {
            const int n = ty * 2 + i;
            const float kgv = kg[(size_t)((((b << 3) + it) << 10) + nloc + n)];
#pragma unroll
            for (int j = 0; j < 4; ++j)
                U[(it << 6) + tx * 4 + j][n] = f2bf((acc[i][j] + bb[j]) * kgv);
        }
    }

    // ---- phase 2: out tiles ----
    for (int jt = 0; jt < 8; ++jt) {
        float acc[2][4] = {};
        // k < 512: A = x, B = w_qkv (q rows) -> qo residual
        for (int kt = 0; kt < 512; kt += 64) {
            {
                const T* xp = x + (size_t)(mbase + xan) * DIMM + kt + xak;
                float v0[4], v1[4];
                load4(xp, v0); load4(xp + 4, v1);
                XA[xak + 0][xan] = v0[0]; XA[xak + 1][xan] = v0[1];
                XA[xak + 2][xan] = v0[2]; XA[xak + 3][xan] = v0[3];
                XA[xak + 4][xan] = v1[0]; XA[xak + 5][xan] = v1[1];
                XA[xak + 6][xan] = v1[2]; XA[xak + 7][xan] = v1[3];
                const T* wp = w_qkv + (size_t)((jt << 6) + wbd) * DIMM + kt + wbk;
#pragma unroll
                for (int q = 0; q < 4; ++q) {
                    float w[4]; load4(wp + q * 4, w);
                    WB[wbk + q * 4 + 0][wbd] = w[0]; WB[wbk + q * 4 + 1][wbd] = w[1];
                    WB[wbk + q * 4 + 2][wbd] = w[2]; WB[wbk + q * 4 + 3][wbd] = w[3];
                }
            }
            __syncthreads();
#pragma unroll
            for (int k = 0; k < 64; ++k) {
                const float a0 = XA[k][ty * 2], a1 = XA[k][ty * 2 + 1];
                float4 b4 = *(const float4*)&WB[k][tx * 4];
                float bv[4] = {b4.x, b4.y, b4.z, b4.w};
#pragma unroll
                for (int j = 0; j < 4; ++j) {
                    acc[0][j] = fmaf(a0, bv[j], acc[0][j]);
                    acc[1][j] = fmaf(a1, bv[j], acc[1][j]);
                }
            }
            __syncthreads();
        }
        // k >= 512: A = U (LDS), B = w_out
        for (int kt = 0; kt < 512; kt += 64) {
            {
                const T* wp = w_out + (size_t)((jt << 6) + wbd) * DIMM + kt + wbk;
#pragma unroll
                for (int q = 0; q < 4; ++q) {
                    float w[4]; load4(wp + q * 4, w);
                    WB[wbk + q * 4 + 0][wbd] = w[0]; WB[wbk + q * 4 + 1][wbd] = w[1];
                    WB[wbk + q * 4 + 2][wbd] = w[2]; WB[wbk + q * 4 + 3][wbd] = w[3];
                }
            }
            __syncthreads();
#pragma unroll
            for (int k = 0; k < 64; ++k) {
                const float a0 = bf2f(U[kt + k][ty * 2]);
                const float a1 = bf2f(U[kt + k][ty * 2 + 1]);
                float4 b4 = *(const float4*)&WB[k][tx * 4];
                float bv[4] = {b4.x, b4.y, b4.z, b4.w};
#pragma unroll
                for (int j = 0; j < 4; ++j) {
                    acc[0][j] = fmaf(a0, bv[j], acc[0][j]);
                    acc[1][j] = fmaf(a1, bv[j], acc[1][j]);
                }
            }
            __syncthreads();
        }
        // epilogue: + b_out + b_qkv(q), store in detected dtype
        float bo[4], bq[4];
        load4(b_out + (jt << 6) + tx * 4, bo);
        load4(b_qkv + (jt << 6) + tx * 4, bq);
        const float bb[4] = {bo[0] + bq[0], bo[1] + bq[1], bo[2] + bq[2], bo[3] + bq[3]};
#pragma unroll
        for (int i = 0; i < 2; ++i) {
            const size_t off = (size_t)(mbase + ty * 2 + i) * DIMM + (jt << 6) + tx * 4;
            if constexpr (sizeof(T) == 2) {
                ushort4 o;
                o.x = f2bf(acc[i][0] + bb[0]); o.y = f2bf(acc[i][1] + bb[1]);
                o.z = f2bf(acc[i][2] + bb[2]); o.w = f2bf(acc[i][3] + bb[3]);
                *(ushort4*)((u16*)outv + off) = o;
            } else {
                float4 o = make_float4(acc[i][0] + bb[0], acc[i][1] + bb[1],
                                       acc[i][2] + bb[2], acc[i][3] + bb[3]);
                *(float4*)((float*)outv + off) = o;
            }
        }
    }
}

// ---------------------------------------------------------------------------
template <typename T>
static void run_all(void* const* d_in, void* d_out, const int* flag,
                    float* qs, float* ks, float* qg, float* kg,
                    float* wsumT, float* bsum, hipStream_t stream)
{
    const T* x     = (const T*)d_in[0];
    const T* w_qkv = (const T*)d_in[1];
    const T* b_qkv = (const T*)d_in[2];
    const T* wq    = (const T*)d_in[3];
    const T* bq    = (const T*)d_in[4];
    const T* wk    = (const T*)d_in[5];
    const T* bk    = (const T*)d_in[6];
    const T* w_out = (const T*)d_in[7];
    const T* b_out = (const T*)d_in[8];

    wsum_kernel<T><<<16, 256, 0, stream>>>(flag, w_qkv, b_qkv, wsumT, bsum);
    qsks_kernel<T><<<512, 256, 0, stream>>>(flag, x, wsumT, bsum, qs, ks);
    stage_kernel<T><<<dim3(16, 64), 256, 0, stream>>>(
        flag, x, w_qkv, b_qkv, 0, wq, bq, nullptr, qs, nullptr, qg);
    stage_kernel<T><<<dim3(16, 64), 256, 0, stream>>>(
        flag, x, w_qkv, b_qkv, 512, wk, bk, qg, qg, ks, kg);
    out_kernel<T><<<256, 256, 0, stream>>>(
        flag, x, w_qkv, b_qkv, w_out, b_out, kg, d_out);
}

extern "C" void kernel_launch(void* const* d_in, const int* in_sizes, int n_in,
                              void* d_out, int out_size, void* d_ws, size_t ws_size,
                              hipStream_t stream)
{
    // workspace: flag(16 f32 slot) | qs|ks|qg|kg (65536 f32 each) | wsumT | bsum
    int*   flag  = (int*)d_ws;
    float* qs    = (float*)d_ws + 16;
    float* ks    = qs + 65536;
    float* qg    = ks + 65536;
    float* kg    = qg + 65536;
    float* wsumT = kg + 65536;
    float* bsum  = wsumT + 8192;

    detect_kernel<<<1, 256, 0, stream>>>((const u16*)d_in[0], flag);
    run_all<float>(d_in, d_out, flag, qs, ks, qg, kg, wsumT, bsum, stream);
    run_all<u16>(d_in, d_out, flag, qs, ks, qg, kg, wsumT, bsum, stream);
}

// Round 5
// 298.890 us; speedup vs baseline: 5.3860x; 5.3860x over previous
//
#include <hip/hip_runtime.h>

// Fastformer additive attention, MI355X (round 4): bf16 MFMA rewrite.
// Inputs/outputs f32 (confirmed round 3). Compute: convert weights to bf16
// once (ws, 2.3 MB), stage x->bf16 per tile, all GEMMs on
// mfma_f32_16x16x32_bf16 (f32 accum). Softmax logits bounded (|l|<~2) ->
// no max subtraction; z/w accumulate across m-tiles, shuffle-reduced.
//
//   q/k/v[b,h,n,d] = x @ w_qkv[{0,512,1024}+h*64+d,:]^T + b_qkv
//   qs/ks row sums via wsum table (f32 VALU kernels)
//   stage1: L1=(q.wq[m]+bq)*S -> qg = sum softmax*qs
//   stage2: L2=(qg*(k.wk[m])+bk)*S -> kg = sum softmax*(qg*ks)
//   out = (kg*v)@w_out^T + x@w_qkv_q^T + b_out + b_qkv_q
//
// MFMA 16x16x32 layouts (guide §3, m89/m120 verified):
//   A: m=lane&15, k=quad*8+i (8 contig bf16)   B: n=lane&15, k=quad*8+i
//   D: row(m)=quad*4+reg, col(n)=lane&15
// LDS strides padded: X/Q/U 520, W-slab 40, wq-tile 72 (2-way aliasing, free).

#define SCL 0.125f
typedef unsigned short u16;
typedef __attribute__((ext_vector_type(8))) short short8;   // 8 bf16 = 4 VGPR
typedef __attribute__((ext_vector_type(4))) float f32x4;

#define MFMA16(a, b, c) __builtin_amdgcn_mfma_f32_16x16x32_bf16((a), (b), (c), 0, 0, 0)

__device__ __forceinline__ u16 f2bf(float f) {
    union { float f; unsigned int i; } v; v.f = f;
    unsigned int x = v.i;
    return (u16)((x + 0x7FFFu + ((x >> 16) & 1u)) >> 16);
}
__device__ __forceinline__ uint4 pack8(const float* v) {
    union { u16 u[8]; uint4 q; } r;
#pragma unroll
    for (int i = 0; i < 8; ++i) r.u[i] = f2bf(v[i]);
    return r.q;
}

// ---- stage 32x512 f32 tile -> bf16 LDS (stride 520) ----
__device__ __forceinline__ void stage_x_tile(const float* __restrict__ xrow0,
                                             u16* __restrict__ Xs, int t) {
    const int row = t & 31, k0 = (t >> 5) * 64;
    const float* xp = xrow0 + (size_t)row * 512 + k0;
    u16* dp = Xs + row * 520 + k0;
#pragma unroll
    for (int i = 0; i < 64; i += 8) {
        float v[8];
        float4 a = *(const float4*)(xp + i);
        float4 c = *(const float4*)(xp + i + 4);
        v[0] = a.x; v[1] = a.y; v[2] = a.z; v[3] = a.w;
        v[4] = c.x; v[5] = c.y; v[6] = c.z; v[7] = c.w;
        *(uint4*)(dp + i) = pack8(v);
    }
}

// ---- stage 256-row x 32-col bf16 weight slab (src stride 512, dst stride 40) ----
__device__ __forceinline__ void stage_w_slab(const u16* __restrict__ wbase,
                                             u16* __restrict__ Ws, int t) {
#pragma unroll
    for (int it = 0; it < 2; ++it) {
        const int c = (t >> 1) + it * 128;
        const int ch = (t & 1) * 16;
        const u16* sp = wbase + (size_t)c * 512 + ch;
        *(uint4*)&Ws[c * 40 + ch]     = *(const uint4*)sp;
        *(uint4*)&Ws[c * 40 + ch + 8] = *(const uint4*)(sp + 8);
    }
}

// ---- acc[16] (idx cc*8+ct*2+rt) += Xs(32x512) @ wsrc(512x512)^T ----
__device__ __forceinline__ void gemm_x_w(const u16* __restrict__ Xs,
                                         const u16* __restrict__ wsrc,
                                         u16* __restrict__ Ws,
                                         int t, int wid, int s, int quad,
                                         f32x4* __restrict__ acc) {
    for (int kt = 0; kt < 512; kt += 32) {
        short8 a0 = *(const short8*)&Xs[s * 520 + kt + quad * 8];
        short8 a1 = *(const short8*)&Xs[(16 + s) * 520 + kt + quad * 8];
#pragma unroll
        for (int cc = 0; cc < 2; ++cc) {
            __syncthreads();
            stage_w_slab(wsrc + (size_t)cc * 256 * 512 + kt, Ws, t);
            __syncthreads();
#pragma unroll
            for (int ct = 0; ct < 4; ++ct) {
                short8 bf = *(const short8*)&Ws[(wid * 64 + ct * 16 + s) * 40 + quad * 8];
                acc[cc * 8 + ct * 2 + 0] = MFMA16(a0, bf, acc[cc * 8 + ct * 2 + 0]);
                acc[cc * 8 + ct * 2 + 1] = MFMA16(a1, bf, acc[cc * 8 + ct * 2 + 1]);
            }
        }
    }
}

// ---------------------------------------------------------------------------
// weight f32 -> bf16 conversion (w_qkv | w_out | wq | wk)
// ---------------------------------------------------------------------------
__global__ __launch_bounds__(256) void conv_kernel(
    const float* __restrict__ w_qkv, const float* __restrict__ w_out,
    const float* __restrict__ wq, const float* __restrict__ wk,
    u16* __restrict__ wqkvb, u16* __restrict__ woutb,
    u16* __restrict__ wqb, u16* __restrict__ wkb)
{
    const int idx = (blockIdx.x * 256 + threadIdx.x) * 4;
    const float* src; u16* dst; int off;
    if      (idx < 786432)  { src = w_qkv; dst = wqkvb; off = idx; }
    else if (idx < 1048576) { src = w_out; dst = woutb; off = idx - 786432; }
    else if (idx < 1114112) { src = wq;    dst = wqb;   off = idx - 1048576; }
    else                    { src = wk;    dst = wkb;   off = idx - 1114112; }
    float4 v = *(const float4*)(src + off);
    ushort4 o; o.x = f2bf(v.x); o.y = f2bf(v.y); o.z = f2bf(v.z); o.w = f2bf(v.w);
    *(ushort4*)(dst + off) = o;
}

// ---------------------------------------------------------------------------
// wsumT[k][c] = sum_d w_qkv[qk*512+h*64+d][k] ; bsum[c] likewise over b_qkv
// ---------------------------------------------------------------------------
__global__ __launch_bounds__(256) void wsum_kernel(
    const float* __restrict__ w_qkv, const float* __restrict__ b_qkv,
    float* __restrict__ wsumT, float* __restrict__ bsum)
{
    const int c = blockIdx.x;           // 0..15
    const int rowbase = (c >> 3) * 512 + (c & 7) * 64;
    for (int k = threadIdx.x; k < 512; k += 256) {
        float s = 0.f;
        for (int d = 0; d < 64; ++d) s += w_qkv[(size_t)(rowbase + d) * 512 + k];
        wsumT[k * 16 + c] = s;
    }
    if (threadIdx.x == 0) {
        float s = 0.f;
        for (int d = 0; d < 64; ++d) s += b_qkv[rowbase + d];
        bsum[c] = s;
    }
}

// ---------------------------------------------------------------------------
// qs[b,h,n] / ks[b,h,n] = x[row].wsumT[:,c] + bsum[c]
// ---------------------------------------------------------------------------
__global__ __launch_bounds__(256) void qsks_kernel(
    const float* __restrict__ x, const float* __restrict__ wsumT,
    const float* __restrict__ bsum, float* __restrict__ qs, float* __restrict__ ks)
{
    __shared__ float X[16][512];
    const int t = threadIdx.x;
    const int rowbase = blockIdx.x * 16;
    {
        const int nr = t >> 4, seg = t & 15;
        const float* xp = x + (size_t)(rowbase + nr) * 512 + seg * 32;
#pragma unroll
        for (int q = 0; q < 8; ++q)
            *(float4*)&X[nr][seg * 32 + q * 4] = *(const float4*)(xp + q * 4);
    }
    __syncthreads();
    const int nr = t >> 4, c = t & 15;
    float dot = bsum[c];
    for (int k = 0; k < 512; ++k) dot += X[nr][k] * wsumT[k * 16 + c];
    const int r = rowbase + nr;
    const int idx = ((((r >> 10) << 3) + (c & 7)) << 10) + (r & 1023);
    if (c < 8) qs[idx] = dot; else ks[idx] = dot;
}

// ---------------------------------------------------------------------------
// Fused stage. Block: (b, 32-row n-tile), all 8 heads (2 per wave).
// Phase1: Q[32n][512c] = X@W^T + bias (MFMA) -> bf16 LDS.
// Phase2: 16 m-tiles of 64: logits MFMA (K=64) + exp/z/w epilogue.
// ---------------------------------------------------------------------------
__global__ __launch_bounds__(256) void stage_mfma(
    const float* __restrict__ x, const u16* __restrict__ wqkvb,
    const float* __restrict__ b_qkv, int aoff,
    const u16* __restrict__ wmb, const float* __restrict__ biasv,
    const float* __restrict__ rowscale, const float* __restrict__ wv1,
    const float* __restrict__ wv2, float* __restrict__ outg)
{
    __shared__ u16 Xs[32 * 520];    // x-tile, then Q-tile (33.3 KB)
    __shared__ u16 Ws[256 * 40];    // weight half-slab / wq-tile (20.5 KB)

    const int t = threadIdx.x;
    const int lane = t & 63, wid = t >> 6;
    const int quad = lane >> 4, s = lane & 15;
    const int n0 = blockIdx.x * 32;
    const int b  = blockIdx.y;

    stage_x_tile(x + (size_t)((b << 10) + n0) * 512, Xs, t);
    __syncthreads();

    // ---- phase 1 ----
    f32x4 acc[16];
#pragma unroll
    for (int i = 0; i < 16; ++i) acc[i] = (f32x4){0.f, 0.f, 0.f, 0.f};
    gemm_x_w(Xs, wqkvb + (size_t)aoff * 512, Ws, t, wid, s, quad, acc);
    __syncthreads();
#pragma unroll
    for (int cc = 0; cc < 2; ++cc)
#pragma unroll
        for (int ct = 0; ct < 4; ++ct) {
            const int c = cc * 256 + wid * 64 + ct * 16 + s;
            const float bias = b_qkv[aoff + c];
#pragma unroll
            for (int rt = 0; rt < 2; ++rt)
#pragma unroll
                for (int r = 0; r < 4; ++r)
                    Xs[(rt * 16 + quad * 4 + r) * 520 + c] =
                        f2bf(acc[cc * 8 + ct * 2 + rt][r] + bias);
        }
    __syncthreads();

    // ---- phase 2 ----
    short8 qa[2][2][2];
    float rs[2][2][4], zz[2][2][4], ww[2][2][4];
#pragma unroll
    for (int h2 = 0; h2 < 2; ++h2) {
        const int h = wid * 2 + h2;
#pragma unroll
        for (int rt = 0; rt < 2; ++rt) {
#pragma unroll
            for (int ks = 0; ks < 2; ++ks)
                qa[h2][rt][ks] = *(const short8*)&Xs[(rt * 16 + s) * 520 + h * 64 + ks * 32 + quad * 8];
#pragma unroll
            for (int r = 0; r < 4; ++r) {
                const int n = n0 + rt * 16 + quad * 4 + r;
                rs[h2][rt][r] = rowscale ? rowscale[(((b << 3) + h) << 10) + n] : 1.0f;
                zz[h2][rt][r] = 0.f; ww[h2][rt][r] = 0.f;
            }
        }
    }

    for (int mt = 0; mt < 1024; mt += 64) {
        __syncthreads();
        {   // stage wq/wk tile [64m][64d] stride 72
            const int g0 = t * 2;
#pragma unroll
            for (int e = 0; e < 2; ++e) {
                const int g = g0 + e, m = g >> 3, ch = (g & 7) * 8;
                *(uint4*)&Ws[m * 72 + ch] = *(const uint4*)(wmb + (size_t)(mt + m) * 64 + ch);
            }
        }
        __syncthreads();
        short8 bf[4][2];
        float bm[4], wvv[2][4];
#pragma unroll
        for (int ct = 0; ct < 4; ++ct) {
#pragma unroll
            for (int ks = 0; ks < 2; ++ks)
                bf[ct][ks] = *(const short8*)&Ws[(ct * 16 + s) * 72 + ks * 32 + quad * 8];
            bm[ct] = biasv[mt + ct * 16 + s];
#pragma unroll
            for (int h2 = 0; h2 < 2; ++h2) {
                const int bh = (b << 3) + wid * 2 + h2;
                float v = wv1[(bh << 10) + mt + ct * 16 + s];
                if (wv2) v *= wv2[(bh << 10) + mt + ct * 16 + s];
                wvv[h2][ct] = v;
            }
        }
#pragma unroll
        for (int h2 = 0; h2 < 2; ++h2)
#pragma unroll
            for (int rt = 0; rt < 2; ++rt)
#pragma unroll
                for (int ct = 0; ct < 4; ++ct) {
                    f32x4 a = (f32x4){0.f, 0.f, 0.f, 0.f};
                    a = MFMA16(qa[h2][rt][0], bf[ct][0], a);
                    a = MFMA16(qa[h2][rt][1], bf[ct][1], a);
#pragma unroll
                    for (int r = 0; r < 4; ++r) {
                        const float l = (rs[h2][rt][r] * a[r] + bm[ct]) * SCL;
                        const float e = __expf(l);
                        zz[h2][rt][r] += e;
                        ww[h2][rt][r] += e * wvv[h2][ct];
                    }
                }
    }

    // ---- reduce across the 16 m-lanes of each quad, write qg/kg ----
#pragma unroll
    for (int h2 = 0; h2 < 2; ++h2)
#pragma unroll
        for (int rt = 0; rt < 2; ++rt)
#pragma unroll
            for (int r = 0; r < 4; ++r) {
                float Z = zz[h2][rt][r], W = ww[h2][rt][r];
                for (int off = 1; off < 16; off <<= 1) {
                    Z += __shfl_xor(Z, off);
                    W += __shfl_xor(W, off);
                }
                if (s == 0) {
                    const int bh = (b << 3) + wid * 2 + h2;
                    outg[(bh << 10) + n0 + rt * 16 + quad * 4 + r] = W / Z;
                }
            }
}

// ---------------------------------------------------------------------------
// Output kernel. Block: 32 rows. Phase A: U = (x@Wv^T+bv)*kg -> bf16 LDS
// (overwrites x-tile). Phase B: out = U@w_out^T + x@w_qkv_q^T + biases
// (x re-staged between halves).
// ---------------------------------------------------------------------------
__global__ __launch_bounds__(256) void out_mfma(
    const float* __restrict__ x, const u16* __restrict__ wqkvb,
    const float* __restrict__ b_qkv, const u16* __restrict__ woutb,
    const float* __restrict__ b_out, const float* __restrict__ kg,
    float* __restrict__ outp)
{
    __shared__ u16 Xs[32 * 520];
    __shared__ u16 Ws[256 * 40];
    __shared__ float kgs[8][32];

    const int t = threadIdx.x;
    const int lane = t & 63, wid = t >> 6;
    const int quad = lane >> 4, s = lane & 15;
    const int r0 = blockIdx.x * 32;
    const int b = r0 >> 10, nl = r0 & 1023;

    stage_x_tile(x + (size_t)r0 * 512, Xs, t);
    {
        const int h = t >> 5, n = t & 31;
        kgs[h][n] = kg[(((b << 3) + h) << 10) + nl + n];
    }
    __syncthreads();

    // ---- phase A: V then U ----
    f32x4 acc[16];
#pragma unroll
    for (int i = 0; i < 16; ++i) acc[i] = (f32x4){0.f, 0.f, 0.f, 0.f};
    gemm_x_w(Xs, wqkvb + (size_t)1024 * 512, Ws, t, wid, s, quad, acc);
    __syncthreads();
#pragma unroll
    for (int cc = 0; cc < 2; ++cc)
#pragma unroll
        for (int ct = 0; ct < 4; ++ct) {
            const int c = cc * 256 + wid * 64 + ct * 16 + s;
            const float bias = b_qkv[1024 + c];
            const int h = c >> 6;
#pragma unroll
            for (int rt = 0; rt < 2; ++rt)
#pragma unroll
                for (int r = 0; r < 4; ++r) {
                    const int n = rt * 16 + quad * 4 + r;
                    Xs[n * 520 + c] = f2bf((acc[cc * 8 + ct * 2 + rt][r] + bias) * kgs[h][n]);
                }
        }
    __syncthreads();

    // ---- phase B: U@w_out^T, then re-stage x and += x@w_qkv_q^T ----
#pragma unroll
    for (int i = 0; i < 16; ++i) acc[i] = (f32x4){0.f, 0.f, 0.f, 0.f};
    gemm_x_w(Xs, woutb, Ws, t, wid, s, quad, acc);
    __syncthreads();
    stage_x_tile(x + (size_t)r0 * 512, Xs, t);
    __syncthreads();
    gemm_x_w(Xs, wqkvb, Ws, t, wid, s, quad, acc);

    // ---- epilogue ----
#pragma unroll
    for (int cc = 0; cc < 2; ++cc)
#pragma unroll
        for (int ct = 0; ct < 4; ++ct) {
            const int j = cc * 256 + wid * 64 + ct * 16 + s;
            const float bias = b_out[j] + b_qkv[j];
#pragma unroll
            for (int rt = 0; rt < 2; ++rt)
#pragma unroll
                for (int r = 0; r < 4; ++r)
                    outp[(size_t)(r0 + rt * 16 + quad * 4 + r) * 512 + j] =
                        acc[cc * 8 + ct * 2 + rt][r] + bias;
        }
}

// ---------------------------------------------------------------------------
extern "C" void kernel_launch(void* const* d_in, const int* in_sizes, int n_in,
                              void* d_out, int out_size, void* d_ws, size_t ws_size,
                              hipStream_t stream)
{
    const float* x     = (const float*)d_in[0];
    const float* w_qkv = (const float*)d_in[1];
    const float* b_qkv = (const float*)d_in[2];
    const float* wq    = (const float*)d_in[3];
    const float* bq    = (const float*)d_in[4];
    const float* wk    = (const float*)d_in[5];
    const float* bk    = (const float*)d_in[6];
    const float* w_out = (const float*)d_in[7];
    const float* b_out = (const float*)d_in[8];
    float* out = (float*)d_out;

    // ws: qs|ks|qg|kg (65536 f32 each) | wsumT 8192 | bsum 16 | bf16 weights
    float* qs    = (float*)d_ws;
    float* ks    = qs + 65536;
    float* qg    = ks + 65536;
    float* kg    = qg + 65536;
    float* wsumT = kg + 65536;
    float* bsum  = wsumT + 8192;
    u16* wqkvb = (u16*)(bsum + 16);
    u16* woutb = wqkvb + 786432;
    u16* wqb   = woutb + 262144;
    u16* wkb   = wqb + 65536;

    conv_kernel<<<1152, 256, 0, stream>>>(w_qkv, w_out, wq, wk, wqkvb, woutb, wqb, wkb);
    wsum_kernel<<<16, 256, 0, stream>>>(w_qkv, b_qkv, wsumT, bsum);
    qsks_kernel<<<512, 256, 0, stream>>>(x, wsumT, bsum, qs, ks);
    stage_mfma<<<dim3(32, 8), 256, 0, stream>>>(
        x, wqkvb, b_qkv, 0, wqb, bq, nullptr, qs, nullptr, qg);
    stage_mfma<<<dim3(32, 8), 256, 0, stream>>>(
        x, wqkvb, b_qkv, 512, wkb, bk, qg, qg, ks, kg);
    out_mfma<<<256, 256, 0, stream>>>(x, wqkvb, b_qkv, woutb, b_out, kg, out);
}

// Round 6
// 221.054 us; speedup vs baseline: 7.2825x; 1.3521x over previous
//
#include <hip/hip_runtime.h>

// Fastformer additive attention, MI355X (round 5): decomposed MFMA pipeline.
//   conv:   w_qkv|w_out|wq|wk f32 -> bf16 (ws)
//   QK:     qk[8192][1024] = x @ w_qkv[0:1024]^T + b_qkv  (bf16 ws, MFMA GEMM)
//   qsks:   qs/ks[bh][n] = per-head row sums of q/k
//   stage1: qg = softmax((q.wq+bq)*S) . qs        (barrier-free MFMA+exp)
//   stage2: kg = softmax((qg*(k.wk)+bk)*S) . (qg*ks)
//   VU:     U = (x @ w_qkv[1024:]^T + bv) * kg    (overlays k-half of qk ws)
//   OUT:    out = U @ w_out^T + b_out + qo        (qo = q-half of qk ws)
// Logits bounded (|l|<~2) -> softmax without max subtraction, z/w linear.
// ws total ~20.1 MB.

#define SCL 0.125f
typedef unsigned short u16;
typedef __attribute__((ext_vector_type(8))) short short8;   // 8 bf16 = 4 VGPR
typedef __attribute__((ext_vector_type(4))) float f32x4;

#define MFMA16(a, b, c) __builtin_amdgcn_mfma_f32_16x16x32_bf16((a), (b), (c), 0, 0, 0)

__device__ __forceinline__ float bf2f(u16 u) {
    union { unsigned int i; float f; } v; v.i = ((unsigned int)u) << 16; return v.f;
}
__device__ __forceinline__ u16 f2bf(float f) {
    union { float f; unsigned int i; } v; v.f = f;
    unsigned int x = v.i;
    return (u16)((x + 0x7FFFu + ((x >> 16) & 1u)) >> 16);
}
__device__ __forceinline__ uint4 pack8(const float* v) {
    union { u16 u[8]; uint4 q; } r;
#pragma unroll
    for (int i = 0; i < 8; ++i) r.u[i] = f2bf(v[i]);
    return r.q;
}

// ---------------------------------------------------------------------------
// weight f32 -> bf16 (w_qkv | w_out | wq | wk)
// ---------------------------------------------------------------------------
__global__ __launch_bounds__(256) void conv_kernel(
    const float* __restrict__ w_qkv, const float* __restrict__ w_out,
    const float* __restrict__ wq, const float* __restrict__ wk,
    u16* __restrict__ wqkvb, u16* __restrict__ woutb,
    u16* __restrict__ wqb, u16* __restrict__ wkb)
{
    const int idx = (blockIdx.x * 256 + threadIdx.x) * 4;
    const float* src; u16* dst; int off;
    if      (idx < 786432)  { src = w_qkv; dst = wqkvb; off = idx; }
    else if (idx < 1048576) { src = w_out; dst = woutb; off = idx - 786432; }
    else if (idx < 1114112) { src = wq;    dst = wqb;   off = idx - 1048576; }
    else                    { src = wk;    dst = wkb;   off = idx - 1114112; }
    float4 v = *(const float4*)(src + off);
    ushort4 o; o.x = f2bf(v.x); o.y = f2bf(v.y); o.z = f2bf(v.z); o.w = f2bf(v.w);
    *(ushort4*)(dst + off) = o;
}

// ---------------------------------------------------------------------------
// Shared MFMA GEMM: tile 128M x 64N, BK=64, K=512, 256 thr (4 waves, each
// 32 rows x 64 cols). Modes: QK (A=x f32, B=wqkv q|k rows, +b_qkv -> bf16 ws),
// VU (A=x, B=wqkv v rows, (+bv)*kg -> bf16 ws col+512), OUT (A=U bf16 ws,
// B=w_out, +b_out+qo -> f32 out). QK/VU bounce C through LDS for coalesced
// bf16 stores.
// ---------------------------------------------------------------------------
#define MQK 0
#define MVU 1
#define MOUT 2

template <int MODE>
__global__ __launch_bounds__(256) void gemm_k(
    const float* __restrict__ x, const u16* __restrict__ qkws_ro,
    const u16* __restrict__ Wb, const float* __restrict__ bias,
    const float* __restrict__ kg,
    u16* __restrict__ qkws, float* __restrict__ outp)
{
    __shared__ u16 As[128 * 72];
    __shared__ u16 Bs[64 * 72];
    const int t = threadIdx.x;
    const int w = t >> 6, lane = t & 63, s = lane & 15, quad = lane >> 4;
    const int bm = blockIdx.x * 128, jn0 = blockIdx.y * 64;

    f32x4 acc[2][4];
#pragma unroll
    for (int i = 0; i < 2; ++i)
#pragma unroll
        for (int j = 0; j < 4; ++j) acc[i][j] = (f32x4){0.f, 0.f, 0.f, 0.f};

    for (int kt = 0; kt < 512; kt += 64) {
        __syncthreads();
        {   // stage A: 128 rows x 64 k
            const int row = t >> 1, ch = (t & 1) * 32;
            if constexpr (MODE == MOUT) {
                const u16* sp = qkws_ro + (size_t)(bm + row) * 1024 + 512 + kt + ch;
#pragma unroll
                for (int i = 0; i < 4; ++i)
                    *(uint4*)&As[row * 72 + ch + i * 8] = *(const uint4*)(sp + i * 8);
            } else {
                const float* sp = x + (size_t)(bm + row) * 512 + kt + ch;
#pragma unroll
                for (int i = 0; i < 4; ++i) {
                    float v[8];
                    float4 a = *(const float4*)(sp + i * 8);
                    float4 c = *(const float4*)(sp + i * 8 + 4);
                    v[0] = a.x; v[1] = a.y; v[2] = a.z; v[3] = a.w;
                    v[4] = c.x; v[5] = c.y; v[6] = c.z; v[7] = c.w;
                    *(uint4*)&As[row * 72 + ch + i * 8] = pack8(v);
                }
            }
            // stage B: 64 rows x 64 k
            const int r = t >> 2, bch = (t & 3) * 16;
            const u16* bp = Wb + (size_t)(jn0 + r) * 512 + kt + bch;
            *(uint4*)&Bs[r * 72 + bch]     = *(const uint4*)bp;
            *(uint4*)&Bs[r * 72 + bch + 8] = *(const uint4*)(bp + 8);
        }
        __syncthreads();
#pragma unroll
        for (int kk = 0; kk < 2; ++kk) {
            short8 a0 = *(const short8*)&As[(w * 32 + s) * 72 + kk * 32 + quad * 8];
            short8 a1 = *(const short8*)&As[(w * 32 + 16 + s) * 72 + kk * 32 + quad * 8];
#pragma unroll
            for (int ct = 0; ct < 4; ++ct) {
                short8 bf = *(const short8*)&Bs[(ct * 16 + s) * 72 + kk * 32 + quad * 8];
                acc[0][ct] = MFMA16(a0, bf, acc[0][ct]);
                acc[1][ct] = MFMA16(a1, bf, acc[1][ct]);
            }
        }
    }

    if constexpr (MODE == MOUT) {
#pragma unroll
        for (int mt = 0; mt < 2; ++mt)
#pragma unroll
            for (int ct = 0; ct < 4; ++ct) {
                const int jn = jn0 + ct * 16 + s;
#pragma unroll
                for (int r = 0; r < 4; ++r) {
                    const int row = bm + w * 32 + mt * 16 + quad * 4 + r;
                    outp[(size_t)row * 512 + jn] =
                        acc[mt][ct][r] + bias[jn] + bf2f(qkws_ro[(size_t)row * 1024 + jn]);
                }
            }
    } else {
        __syncthreads();
#pragma unroll
        for (int mt = 0; mt < 2; ++mt)
#pragma unroll
            for (int ct = 0; ct < 4; ++ct) {
                const int jn = jn0 + ct * 16 + s;
#pragma unroll
                for (int r = 0; r < 4; ++r) {
                    const int rowl = w * 32 + mt * 16 + quad * 4 + r;
                    float v = acc[mt][ct][r] + bias[jn];
                    if constexpr (MODE == MVU) {
                        const int row = bm + rowl;
                        v *= kg[(((row >> 10) * 8 + (jn >> 6)) << 10) | (row & 1023)];
                    }
                    As[rowl * 72 + ct * 16 + s] = f2bf(v);
                }
            }
        __syncthreads();
        const int row = t >> 1, ch = (t & 1) * 32;
        u16* dp = qkws + (size_t)(bm + row) * 1024 + (MODE == MVU ? 512 : 0) + jn0 + ch;
#pragma unroll
        for (int i = 0; i < 4; ++i)
            *(uint4*)(dp + i * 8) = *(const uint4*)&As[row * 72 + ch + i * 8];
    }
}

// ---------------------------------------------------------------------------
// qs[bh,n] / ks[bh,n] from stored q/k (bf16 ws)
// ---------------------------------------------------------------------------
__global__ __launch_bounds__(256) void qsks_kernel(
    const u16* __restrict__ qkws, float* __restrict__ qs, float* __restrict__ ks)
{
    const int tid = blockIdx.x * 256 + threadIdx.x;  // bh*1024 + n
    const int n = tid & 1023, bh = tid >> 10, b = bh >> 3, h = bh & 7;
    const u16* base = qkws + (size_t)((b << 10) + n) * 1024 + (h << 6);
    float sq = 0.f, sk = 0.f;
#pragma unroll
    for (int i = 0; i < 64; i += 8) {
        union { uint4 q; u16 u[8]; } a, c;
        a.q = *(const uint4*)(base + i);
        c.q = *(const uint4*)(base + 512 + i);
#pragma unroll
        for (int j = 0; j < 8; ++j) { sq += bf2f(a.u[j]); sk += bf2f(c.u[j]); }
    }
    qs[tid] = sq; ks[tid] = sk;
}

// ---------------------------------------------------------------------------
// Softmax stage, barrier-free hot loop. Block: 64 n-rows x one (b,h); wave w
// covers m in [w*256, w*256+256). A-frags (Q rows) from ws bf16; B-frags
// (wq/wk rows) straight from global (L2-hot). exp/z/w in registers,
// shfl-reduce over the 16 m-lanes, one LDS reduce across waves.
//   stage1: qcol0=0,   rowscale=null, wv=qs
//   stage2: qcol0=512, rowscale=qg,   wv=qg*ks
// ---------------------------------------------------------------------------
__global__ __launch_bounds__(256) void stage_soft(
    const u16* __restrict__ qkws, int qcol0,
    const u16* __restrict__ wmb, const float* __restrict__ biasv,
    const float* __restrict__ rowscale,
    const float* __restrict__ wv1, const float* __restrict__ wv2,
    float* __restrict__ outg)
{
    __shared__ float zr[4][64], wr[4][64];
    const int t = threadIdx.x;
    const int w = t >> 6, lane = t & 63, s = lane & 15, quad = lane >> 4;
    const int n0 = blockIdx.x * 64;
    const int bh = blockIdx.y, b = bh >> 3, h = bh & 7;

    short8 qa[4][2];
#pragma unroll
    for (int nt = 0; nt < 4; ++nt)
#pragma unroll
        for (int kk = 0; kk < 2; ++kk)
            qa[nt][kk] = *(const short8*)&qkws[
                (size_t)((b << 10) + n0 + nt * 16 + s) * 1024 + qcol0 + (h << 6) + kk * 32 + quad * 8];

    float rs[4][4];
#pragma unroll
    for (int nt = 0; nt < 4; ++nt)
#pragma unroll
        for (int r = 0; r < 4; ++r)
            rs[nt][r] = rowscale ? rowscale[(bh << 10) + n0 + nt * 16 + quad * 4 + r] : 1.0f;

    float z[4][4] = {}, wa[4][4] = {};

    for (int mi = 0; mi < 16; ++mi) {
        const int mt = w * 256 + mi * 16;
        const u16* bp = wmb + (size_t)(mt + s) * 64 + quad * 8;
        short8 bf0 = *(const short8*)bp;
        short8 bf1 = *(const short8*)(bp + 32);
        const float bm = biasv[mt + s];
        float wv = wv1[(bh << 10) + mt + s];
        if (wv2) wv *= wv2[(bh << 10) + mt + s];
#pragma unroll
        for (int nt = 0; nt < 4; ++nt) {
            f32x4 a = (f32x4){0.f, 0.f, 0.f, 0.f};
            a = MFMA16(qa[nt][0], bf0, a);
            a = MFMA16(qa[nt][1], bf1, a);
#pragma unroll
            for (int r = 0; r < 4; ++r) {
                const float l = (rs[nt][r] * a[r] + bm) * SCL;
                const float e = __expf(l);
                z[nt][r] += e;
                wa[nt][r] += e * wv;
            }
        }
    }

    // reduce over the 16 m-lanes of each quad, then across waves via LDS
#pragma unroll
    for (int nt = 0; nt < 4; ++nt)
#pragma unroll
        for (int r = 0; r < 4; ++r) {
            float Z = z[nt][r], W = wa[nt][r];
            for (int off = 1; off < 16; off <<= 1) {
                Z += __shfl_xor(Z, off);
                W += __shfl_xor(W, off);
            }
            if (s == 0) {
                zr[w][nt * 16 + quad * 4 + r] = Z;
                wr[w][nt * 16 + quad * 4 + r] = W;
            }
        }
    __syncthreads();
    if (t < 64) {
        float Z = zr[0][t] + zr[1][t] + zr[2][t] + zr[3][t];
        float W = wr[0][t] + wr[1][t] + wr[2][t] + wr[3][t];
        outg[(bh << 10) + n0 + t] = W / Z;
    }
}

// ---------------------------------------------------------------------------
extern "C" void kernel_launch(void* const* d_in, const int* in_sizes, int n_in,
                              void* d_out, int out_size, void* d_ws, size_t ws_size,
                              hipStream_t stream)
{
    const float* x     = (const float*)d_in[0];
    const float* w_qkv = (const float*)d_in[1];
    const float* b_qkv = (const float*)d_in[2];
    const float* wq    = (const float*)d_in[3];
    const float* bq    = (const float*)d_in[4];
    const float* wk    = (const float*)d_in[5];
    const float* bk    = (const float*)d_in[6];
    const float* w_out = (const float*)d_in[7];
    const float* b_out = (const float*)d_in[8];
    float* out = (float*)d_out;

    // ws: qs|ks|qg|kg (65536 f32) | bf16 weights | qk ws [8192][1024] bf16
    float* qs = (float*)d_ws;
    float* ks = qs + 65536;
    float* qg = ks + 65536;
    float* kg = qg + 65536;
    u16* wqkvb = (u16*)(kg + 65536);
    u16* woutb = wqkvb + 786432;
    u16* wqb   = woutb + 262144;
    u16* wkb   = wqb + 65536;
    u16* qkws  = wkb + 65536;

    conv_kernel<<<1152, 256, 0, stream>>>(w_qkv, w_out, wq, wk, wqkvb, woutb, wqb, wkb);
    // QK: qk = x @ w_qkv[0:1024]^T + b_qkv
    gemm_k<MQK><<<dim3(64, 16), 256, 0, stream>>>(
        x, nullptr, wqkvb, b_qkv, nullptr, qkws, nullptr);
    qsks_kernel<<<256, 256, 0, stream>>>(qkws, qs, ks);
    // stage 1 -> qg
    stage_soft<<<dim3(16, 64), 256, 0, stream>>>(
        qkws, 0, wqb, bq, nullptr, qs, nullptr, qg);
    // stage 2 -> kg
    stage_soft<<<dim3(16, 64), 256, 0, stream>>>(
        qkws, 512, wkb, bk, qg, qg, ks, kg);
    // VU: U = (x @ w_qkv[1024:]^T + bv) * kg  (into k-half of qk ws)
    gemm_k<MVU><<<dim3(64, 8), 256, 0, stream>>>(
        x, nullptr, wqkvb + (size_t)1024 * 512, b_qkv + 1024, kg, qkws, nullptr);
    // OUT: out = U @ w_out^T + b_out + qo
    gemm_k<MOUT><<<dim3(64, 8), 256, 0, stream>>>(
        nullptr, qkws, woutb, b_out, nullptr, nullptr, out);
}

// Round 7
// 189.947 us; speedup vs baseline: 8.4752x; 1.1638x over previous
//
#include <hip/hip_runtime.h>

// Fastformer additive attention, MI355X (round 6): hoisted bf16 conversion.
//   conv:   w_qkv|w_out|wq|wk|x  f32 -> bf16 (ws)          [one pass]
//   QK:     qk[8192][1024] = x @ w_qkv[0:1024]^T + b_qkv   (bf16 ws, MFMA)
//   qsks:   qs/ks[bh][n] = per-head row sums of q/k
//   stage1: qg = softmax((q.wq+bq)*S) . qs                 (barrier-free)
//   stage2: kg = softmax((qg*(k.wk)+bk)*S) . (qg*ks)
//   VU:     U = (x @ w_qkv[1024:]^T + bv) * kg   (k-half of qk ws)
//   OUT:    out = U @ w_out^T + b_out + qo       (qo = q-half of qk ws)
// Logits bounded (|l|<~2) -> softmax without max subtraction, z/w linear.
// ws total ~28.5 MB.

#define SCL 0.125f
typedef unsigned short u16;
typedef __attribute__((ext_vector_type(8))) short short8;   // 8 bf16 = 4 VGPR
typedef __attribute__((ext_vector_type(4))) float f32x4;

#define MFMA16(a, b, c) __builtin_amdgcn_mfma_f32_16x16x32_bf16((a), (b), (c), 0, 0, 0)

__device__ __forceinline__ float bf2f(u16 u) {
    union { unsigned int i; float f; } v; v.i = ((unsigned int)u) << 16; return v.f;
}
__device__ __forceinline__ u16 f2bf(float f) {
    union { float f; unsigned int i; } v; v.f = f;
    unsigned int x = v.i;
    return (u16)((x + 0x7FFFu + ((x >> 16) & 1u)) >> 16);
}

// ---------------------------------------------------------------------------
// f32 -> bf16: w_qkv | w_out | wq | wk | x   (contiguous ws block)
// ---------------------------------------------------------------------------
__global__ __launch_bounds__(256) void conv_kernel(
    const float* __restrict__ w_qkv, const float* __restrict__ w_out,
    const float* __restrict__ wq, const float* __restrict__ wk,
    const float* __restrict__ x, u16* __restrict__ wsb)
{
    const int idx = (blockIdx.x * 256 + threadIdx.x) * 4;
    const float* src; int off;
    if      (idx < 786432)  { src = w_qkv; off = idx; }
    else if (idx < 1048576) { src = w_out; off = idx - 786432; }
    else if (idx < 1114112) { src = wq;    off = idx - 1048576; }
    else if (idx < 1179648) { src = wk;    off = idx - 1114112; }
    else                    { src = x;     off = idx - 1179648; }
    float4 v = *(const float4*)(src + off);
    ushort4 o; o.x = f2bf(v.x); o.y = f2bf(v.y); o.z = f2bf(v.z); o.w = f2bf(v.w);
    *(ushort4*)(wsb + idx) = o;
}

// ---------------------------------------------------------------------------
// Shared MFMA GEMM: tile 128M x 64N, BK=64, K=512, 256 thr (4 waves, each
// 32 rows x 64 cols). A is bf16 (xb or U-half of qkws); B is bf16 weights.
// Modes: QK (+b_qkv -> bf16 qkws), VU ((+bv)*kg -> qkws col+512),
// OUT (+b_out+qo -> f32 out). QK/VU bounce C through LDS (coalesced stores).
// ---------------------------------------------------------------------------
#define MQK 0
#define MVU 1
#define MOUT 2

template <int MODE>
__global__ __launch_bounds__(256) void gemm_k(
    const u16* __restrict__ Ab, int lda, int acol,
    const u16* __restrict__ Wb, const float* __restrict__ bias,
    const float* __restrict__ kg, const u16* __restrict__ qkws_ro,
    u16* __restrict__ qkws, float* __restrict__ outp)
{
    __shared__ u16 As[128 * 72];
    __shared__ u16 Bs[64 * 72];
    const int t = threadIdx.x;
    const int w = t >> 6, lane = t & 63, s = lane & 15, quad = lane >> 4;
    const int bm = blockIdx.x * 128, jn0 = blockIdx.y * 64;

    f32x4 acc[2][4];
#pragma unroll
    for (int i = 0; i < 2; ++i)
#pragma unroll
        for (int j = 0; j < 4; ++j) acc[i][j] = (f32x4){0.f, 0.f, 0.f, 0.f};

    for (int kt = 0; kt < 512; kt += 64) {
        __syncthreads();
        {   // stage A: 128 rows x 64 k (pure bf16 copy)
            const int row = t >> 1, ch = (t & 1) * 32;
            const u16* sp = Ab + (size_t)(bm + row) * lda + acol + kt + ch;
#pragma unroll
            for (int i = 0; i < 4; ++i)
                *(uint4*)&As[row * 72 + ch + i * 8] = *(const uint4*)(sp + i * 8);
            // stage B: 64 rows x 64 k
            const int r = t >> 2, bch = (t & 3) * 16;
            const u16* bp = Wb + (size_t)(jn0 + r) * 512 + kt + bch;
            *(uint4*)&Bs[r * 72 + bch]     = *(const uint4*)bp;
            *(uint4*)&Bs[r * 72 + bch + 8] = *(const uint4*)(bp + 8);
        }
        __syncthreads();
#pragma unroll
        for (int kk = 0; kk < 2; ++kk) {
            short8 a0 = *(const short8*)&As[(w * 32 + s) * 72 + kk * 32 + quad * 8];
            short8 a1 = *(const short8*)&As[(w * 32 + 16 + s) * 72 + kk * 32 + quad * 8];
#pragma unroll
            for (int ct = 0; ct < 4; ++ct) {
                short8 bf = *(const short8*)&Bs[(ct * 16 + s) * 72 + kk * 32 + quad * 8];
                acc[0][ct] = MFMA16(a0, bf, acc[0][ct]);
                acc[1][ct] = MFMA16(a1, bf, acc[1][ct]);
            }
        }
    }

    if constexpr (MODE == MOUT) {
#pragma unroll
        for (int mt = 0; mt < 2; ++mt)
#pragma unroll
            for (int ct = 0; ct < 4; ++ct) {
                const int jn = jn0 + ct * 16 + s;
#pragma unroll
                for (int r = 0; r < 4; ++r) {
                    const int row = bm + w * 32 + mt * 16 + quad * 4 + r;
                    outp[(size_t)row * 512 + jn] =
                        acc[mt][ct][r] + bias[jn] + bf2f(qkws_ro[(size_t)row * 1024 + jn]);
                }
            }
    } else {
        __syncthreads();
#pragma unroll
        for (int mt = 0; mt < 2; ++mt)
#pragma unroll
            for (int ct = 0; ct < 4; ++ct) {
                const int jn = jn0 + ct * 16 + s;
#pragma unroll
                for (int r = 0; r < 4; ++r) {
                    const int rowl = w * 32 + mt * 16 + quad * 4 + r;
                    float v = acc[mt][ct][r] + bias[jn];
                    if constexpr (MODE == MVU) {
                        const int row = bm + rowl;
                        v *= kg[(((row >> 10) * 8 + (jn >> 6)) << 10) | (row & 1023)];
                    }
                    As[rowl * 72 + ct * 16 + s] = f2bf(v);
                }
            }
        __syncthreads();
        const int row = t >> 1, ch = (t & 1) * 32;
        u16* dp = qkws + (size_t)(bm + row) * 1024 + (MODE == MVU ? 512 : 0) + jn0 + ch;
#pragma unroll
        for (int i = 0; i < 4; ++i)
            *(uint4*)(dp + i * 8) = *(const uint4*)&As[row * 72 + ch + i * 8];
    }
}

// ---------------------------------------------------------------------------
// qs[bh,n] / ks[bh,n] from stored q/k (bf16 ws)
// ---------------------------------------------------------------------------
__global__ __launch_bounds__(256) void qsks_kernel(
    const u16* __restrict__ qkws, float* __restrict__ qs, float* __restrict__ ks)
{
    const int tid = blockIdx.x * 256 + threadIdx.x;  // bh*1024 + n
    const int n = tid & 1023, bh = tid >> 10, b = bh >> 3, h = bh & 7;
    const u16* base = qkws + (size_t)((b << 10) + n) * 1024 + (h << 6);
    float sq = 0.f, sk = 0.f;
#pragma unroll
    for (int i = 0; i < 64; i += 8) {
        union { uint4 q; u16 u[8]; } a, c;
        a.q = *(const uint4*)(base + i);
        c.q = *(const uint4*)(base + 512 + i);
#pragma unroll
        for (int j = 0; j < 8; ++j) { sq += bf2f(a.u[j]); sk += bf2f(c.u[j]); }
    }
    qs[tid] = sq; ks[tid] = sk;
}

// ---------------------------------------------------------------------------
// Softmax stage, barrier-free hot loop. Block: 64 n-rows x one (b,h); wave w
// covers m in [w*256, w*256+256). A-frags (Q rows) from ws bf16; B-frags
// (wq/wk rows) straight from global (L2-hot). exp/z/w in registers,
// shfl-reduce over the 16 m-lanes, one LDS reduce across waves.
//   stage1: qcol0=0,   rowscale=null, wv=qs
//   stage2: qcol0=512, rowscale=qg,   wv=qg*ks
// ---------------------------------------------------------------------------
__global__ __launch_bounds__(256) void stage_soft(
    const u16* __restrict__ qkws, int qcol0,
    const u16* __restrict__ wmb, const float* __restrict__ biasv,
    const float* __restrict__ rowscale,
    const float* __restrict__ wv1, const float* __restrict__ wv2,
    float* __restrict__ outg)
{
    __shared__ float zr[4][64], wr[4][64];
    const int t = threadIdx.x;
    const int w = t >> 6, lane = t & 63, s = lane & 15, quad = lane >> 4;
    const int n0 = blockIdx.x * 64;
    const int bh = blockIdx.y, b = bh >> 3, h = bh & 7;

    short8 qa[4][2];
#pragma unroll
    for (int nt = 0; nt < 4; ++nt)
#pragma unroll
        for (int kk = 0; kk < 2; ++kk)
            qa[nt][kk] = *(const short8*)&qkws[
                (size_t)((b << 10) + n0 + nt * 16 + s) * 1024 + qcol0 + (h << 6) + kk * 32 + quad * 8];

    float rs[4][4];
#pragma unroll
    for (int nt = 0; nt < 4; ++nt)
#pragma unroll
        for (int r = 0; r < 4; ++r)
            rs[nt][r] = rowscale ? rowscale[(bh << 10) + n0 + nt * 16 + quad * 4 + r] : 1.0f;

    float z[4][4] = {}, wa[4][4] = {};

    for (int mi = 0; mi < 16; ++mi) {
        const int mt = w * 256 + mi * 16;
        const u16* bp = wmb + (size_t)(mt + s) * 64 + quad * 8;
        short8 bf0 = *(const short8*)bp;
        short8 bf1 = *(const short8*)(bp + 32);
        const float bm = biasv[mt + s];
        float wv = wv1[(bh << 10) + mt + s];
        if (wv2) wv *= wv2[(bh << 10) + mt + s];
#pragma unroll
        for (int nt = 0; nt < 4; ++nt) {
            f32x4 a = (f32x4){0.f, 0.f, 0.f, 0.f};
            a = MFMA16(qa[nt][0], bf0, a);
            a = MFMA16(qa[nt][1], bf1, a);
#pragma unroll
            for (int r = 0; r < 4; ++r) {
                const float l = (rs[nt][r] * a[r] + bm) * SCL;
                const float e = __expf(l);
                z[nt][r] += e;
                wa[nt][r] += e * wv;
            }
        }
    }

    // reduce over the 16 m-lanes of each quad, then across waves via LDS
#pragma unroll
    for (int nt = 0; nt < 4; ++nt)
#pragma unroll
        for (int r = 0; r < 4; ++r) {
            float Z = z[nt][r], W = wa[nt][r];
            for (int off = 1; off < 16; off <<= 1) {
                Z += __shfl_xor(Z, off);
                W += __shfl_xor(W, off);
            }
            if (s == 0) {
                zr[w][nt * 16 + quad * 4 + r] = Z;
                wr[w][nt * 16 + quad * 4 + r] = W;
            }
        }
    __syncthreads();
    if (t < 64) {
        float Z = zr[0][t] + zr[1][t] + zr[2][t] + zr[3][t];
        float W = wr[0][t] + wr[1][t] + wr[2][t] + wr[3][t];
        outg[(bh << 10) + n0 + t] = W / Z;
    }
}

// ---------------------------------------------------------------------------
extern "C" void kernel_launch(void* const* d_in, const int* in_sizes, int n_in,
                              void* d_out, int out_size, void* d_ws, size_t ws_size,
                              hipStream_t stream)
{
    const float* x     = (const float*)d_in[0];
    const float* w_qkv = (const float*)d_in[1];
    const float* b_qkv = (const float*)d_in[2];
    const float* wq    = (const float*)d_in[3];
    const float* bq    = (const float*)d_in[4];
    const float* wk    = (const float*)d_in[5];
    const float* bk    = (const float*)d_in[6];
    const float* w_out = (const float*)d_in[7];
    const float* b_out = (const float*)d_in[8];
    float* out = (float*)d_out;

    // ws: qs|ks|qg|kg (65536 f32) | bf16: wqkv|wout|wq|wk|x | qk ws bf16
    float* qs = (float*)d_ws;
    float* ks = qs + 65536;
    float* qg = ks + 65536;
    float* kg = qg + 65536;
    u16* wsb   = (u16*)(kg + 65536);
    u16* wqkvb = wsb;
    u16* woutb = wqkvb + 786432;
    u16* wqb   = woutb + 262144;
    u16* wkb   = wqb + 65536;
    u16* xb    = wkb + 65536;
    u16* qkws  = xb + 4194304;

    // 5,373,952 f32 -> bf16 (weights + x), 4 elems/thread
    conv_kernel<<<5248, 256, 0, stream>>>(w_qkv, w_out, wq, wk, x, wsb);
    // QK: qk = x @ w_qkv[0:1024]^T + b_qkv
    gemm_k<MQK><<<dim3(64, 16), 256, 0, stream>>>(
        xb, 512, 0, wqkvb, b_qkv, nullptr, nullptr, qkws, nullptr);
    qsks_kernel<<<256, 256, 0, stream>>>(qkws, qs, ks);
    // stage 1 -> qg
    stage_soft<<<dim3(16, 64), 256, 0, stream>>>(
        qkws, 0, wqb, bq, nullptr, qs, nullptr, qg);
    // stage 2 -> kg
    stage_soft<<<dim3(16, 64), 256, 0, stream>>>(
        qkws, 512, wkb, bk, qg, qg, ks, kg);
    // VU: U = (x @ w_qkv[1024:]^T + bv) * kg  (into k-half of qk ws)
    gemm_k<MVU><<<dim3(64, 8), 256, 0, stream>>>(
        xb, 512, 0, wqkvb + (size_t)1024 * 512, b_qkv + 1024, kg, nullptr, qkws, nullptr);
    // OUT: out = U @ w_out^T + b_out + qo
    gemm_k<MOUT><<<dim3(64, 8), 256, 0, stream>>>(
        qkws, 1024, 512, woutb, b_out, nullptr, qkws, nullptr, out);
}